// Round 1
// baseline (728.335 us; speedup 1.0000x reference)
//
#include <hip/hip_runtime.h>
#include <stdint.h>

using bf16x8 = __attribute__((ext_vector_type(8))) short;
using f32x4  = __attribute__((ext_vector_type(4))) float;

#define DEVI static __device__ __forceinline__

DEVI unsigned short f2bf(float f) {
  union { float f; unsigned int u; } v; v.f = f;
  return (unsigned short)((v.u + 0x7FFFu + ((v.u >> 16) & 1u)) >> 16);
}

DEVI void async_cp16(const void* g, void* l) {
  __builtin_amdgcn_global_load_lds((__attribute__((address_space(1))) void*)g,
                                   (__attribute__((address_space(3))) void*)l,
                                   16, 0, 0);
}

// ---------- f32 -> bf16 elementwise (x) ----------
__global__ __launch_bounds__(256) void k_cvt(const float* __restrict__ X,
                                             unsigned short* __restrict__ Xb, int n4) {
  int i = blockIdx.x * 256 + threadIdx.x;
  if (i >= n4) return;
  float4 v = ((const float4*)X)[i];
  ushort4 o;
  o.x = f2bf(v.x); o.y = f2bf(v.y); o.z = f2bf(v.z); o.w = f2bf(v.w);
  ((ushort4*)Xb)[i] = o;
}

// ---------- W[Kd][N] f32 -> Wt[N][Kd] bf16 ----------
__global__ __launch_bounds__(1024) void k_transpose(const float* __restrict__ W,
                                                    unsigned short* __restrict__ Wt,
                                                    int Kd, int N) {
  __shared__ float tile[32][33];
  int n0 = blockIdx.x * 32, k0 = blockIdx.y * 32;
  int tx = threadIdx.x, ty = threadIdx.y;
  tile[ty][tx] = W[(size_t)(k0 + ty) * N + n0 + tx];
  __syncthreads();
  Wt[(size_t)(n0 + ty) * Kd + k0 + tx] = f2bf(tile[tx][ty]);
}

// ---------- GEMM1: [8192x768] x [768x2304] -> scatter Q,K,Vt (bf16) ----------
__global__ __launch_bounds__(256) void k_gemm_qkv(
    const unsigned short* __restrict__ A,   // x bf16 [8192][768]
    const unsigned short* __restrict__ Bt,  // wqkvT bf16 [2304][768]
    unsigned short* __restrict__ Q,
    unsigned short* __restrict__ K,
    unsigned short* __restrict__ Vt) {
  __shared__ unsigned short As[128 * 32];
  __shared__ unsigned short Bs[128 * 32];
  const int t = threadIdx.x;
  const int w = t >> 6, l = t & 63;
  const int l15 = l & 15, q4 = l >> 4;
  const int wm = w >> 1, wn = w & 1;
  const int m0 = blockIdx.y * 128, n0 = blockIdx.x * 128;

  f32x4 acc[4][4];
#pragma unroll
  for (int i = 0; i < 4; ++i)
#pragma unroll
    for (int j = 0; j < 4; ++j) acc[i][j] = f32x4{0.f, 0.f, 0.f, 0.f};

  const int f2 = t + 256;
  const int ra = t >> 2, ca = (t & 3) * 8;
  const int ra2 = f2 >> 2, ca2 = (f2 & 3) * 8;

  for (int kt = 0; kt < 24; ++kt) {
    const int k0 = kt * 32;
    async_cp16(A + (size_t)(m0 + ra) * 768 + k0 + ca, &As[w * 512]);
    async_cp16(A + (size_t)(m0 + ra2) * 768 + k0 + ca2, &As[2048 + w * 512]);
    async_cp16(Bt + (size_t)(n0 + ra) * 768 + k0 + ca, &Bs[w * 512]);
    async_cp16(Bt + (size_t)(n0 + ra2) * 768 + k0 + ca2, &Bs[2048 + w * 512]);
    __syncthreads();
    bf16x8 a[4], b[4];
#pragma unroll
    for (int mt = 0; mt < 4; ++mt)
      a[mt] = *(const bf16x8*)&As[(wm * 64 + mt * 16 + l15) * 32 + q4 * 8];
#pragma unroll
    for (int nt = 0; nt < 4; ++nt)
      b[nt] = *(const bf16x8*)&Bs[(wn * 64 + nt * 16 + l15) * 32 + q4 * 8];
#pragma unroll
    for (int mt = 0; mt < 4; ++mt)
#pragma unroll
      for (int nt = 0; nt < 4; ++nt)
        acc[mt][nt] = __builtin_amdgcn_mfma_f32_16x16x32_bf16(a[mt], b[nt], acc[mt][nt], 0, 0, 0);
    __syncthreads();
  }

  const int which = n0 / 768;  // 0=q 1=k 2=v (128 | 768, so uniform per block)
#pragma unroll
  for (int mt = 0; mt < 4; ++mt)
#pragma unroll
    for (int nt = 0; nt < 4; ++nt)
#pragma unroll
      for (int r = 0; r < 4; ++r) {
        const int m = m0 + wm * 64 + mt * 16 + q4 * 4 + r;
        const int n = n0 + wn * 64 + nt * 16 + l15;
        const int c = n - which * 768;
        const int h = c >> 6, d = c & 63;
        const int bb = m >> 10, nn = m & 1023;
        const int bh = bb * 12 + h;
        const unsigned short val = f2bf(acc[mt][nt][r]);
        if (which == 0)
          Q[(size_t)(bh * 1024 + nn) * 64 + d] = val;
        else if (which == 1)
          K[(size_t)(bh * 1024 + nn) * 64 + d] = val;
        else
          Vt[(size_t)(bh * 64 + d) * 1024 + nn] = val;  // transposed for PV B-frags
      }
}

// ---------- attention: per (bh, 64 q-rows); online softmax; attn + ctx ----------
__global__ __launch_bounds__(256) void k_attn(
    const unsigned short* __restrict__ Q,
    const unsigned short* __restrict__ Kg,
    const unsigned short* __restrict__ Vt,
    float* __restrict__ attn,
    unsigned short* __restrict__ ctx) {
  __shared__ unsigned short qs[64 * 64];
  __shared__ unsigned short ks[64 * 64];
  __shared__ unsigned short vs[64 * 64];             // [d][key_local]
  __shared__ unsigned short pshm[4][16 * 80];        // per-wave P strip, stride 80 (16B-aligned rows)
  __shared__ float m_hist[64][16];
  __shared__ float mf[64], lf[64];

  const int t = threadIdx.x;
  const int w = t >> 6, l = t & 63;
  const int l15 = l & 15, q4 = l >> 4;
  const int qb = blockIdx.x, bh = blockIdx.y;
  const int qbase = qb * 64;

  {  // stage Q tile once (contiguous 8 KiB)
    const size_t qoff = ((size_t)bh * 1024 + qbase) * 64;
    async_cp16(Q + qoff + (size_t)t * 8, &qs[w * 512]);
    async_cp16(Q + qoff + (size_t)(t + 256) * 8, &qs[2048 + w * 512]);
  }

  float m_r[4], l_r[4];
#pragma unroll
  for (int r = 0; r < 4; ++r) { m_r[r] = -__builtin_inff(); l_r[r] = 0.f; }
  f32x4 o[4];
#pragma unroll
  for (int dt = 0; dt < 4; ++dt) o[dt] = f32x4{0.f, 0.f, 0.f, 0.f};

  float* const attn_bh = attn + ((size_t)bh << 20);
  const int vrow = t >> 3, vcol = (t & 7) * 8;
  const int vrow2 = (t + 256) >> 3, vcol2 = ((t + 256) & 7) * 8;

  for (int kt = 0; kt < 16; ++kt) {
    {
      const size_t koff = ((size_t)bh * 1024 + kt * 64) * 64;
      async_cp16(Kg + koff + (size_t)t * 8, &ks[w * 512]);
      async_cp16(Kg + koff + (size_t)(t + 256) * 8, &ks[2048 + w * 512]);
      const size_t vbase = (size_t)bh * 65536 + kt * 64;
      async_cp16(Vt + vbase + (size_t)vrow * 1024 + vcol, &vs[w * 512]);
      async_cp16(Vt + vbase + (size_t)vrow2 * 1024 + vcol2, &vs[2048 + w * 512]);
    }
    __syncthreads();

    // S = (Q Kt) * scale ; wave w owns q-rows w*16..w*16+15
    const bf16x8 aq0 = *(const bf16x8*)&qs[(w * 16 + l15) * 64 + q4 * 8];
    const bf16x8 aq1 = *(const bf16x8*)&qs[(w * 16 + l15) * 64 + 32 + q4 * 8];
    f32x4 s[4];
#pragma unroll
    for (int nt = 0; nt < 4; ++nt) {
      const bf16x8 bk0 = *(const bf16x8*)&ks[(nt * 16 + l15) * 64 + q4 * 8];
      const bf16x8 bk1 = *(const bf16x8*)&ks[(nt * 16 + l15) * 64 + 32 + q4 * 8];
      f32x4 z = f32x4{0.f, 0.f, 0.f, 0.f};
      z = __builtin_amdgcn_mfma_f32_16x16x32_bf16(aq0, bk0, z, 0, 0, 0);
      z = __builtin_amdgcn_mfma_f32_16x16x32_bf16(aq1, bk1, z, 0, 0, 0);
      s[nt] = z * 0.125f;
    }

    // online softmax (rows live in quads: row = q4*4 + r)
    float mnew[4], alpha[4];
#pragma unroll
    for (int r = 0; r < 4; ++r) {
      float x = fmaxf(fmaxf(s[0][r], s[1][r]), fmaxf(s[2][r], s[3][r]));
      x = fmaxf(x, __shfl_xor(x, 1, 64));
      x = fmaxf(x, __shfl_xor(x, 2, 64));
      x = fmaxf(x, __shfl_xor(x, 4, 64));
      x = fmaxf(x, __shfl_xor(x, 8, 64));
      mnew[r] = fmaxf(m_r[r], x);
      alpha[r] = __expf(m_r[r] - mnew[r]);
    }
    f32x4 p[4];
#pragma unroll
    for (int nt = 0; nt < 4; ++nt)
#pragma unroll
      for (int r = 0; r < 4; ++r) p[nt][r] = __expf(s[nt][r] - mnew[r]);
#pragma unroll
    for (int r = 0; r < 4; ++r) {
      float su = p[0][r] + p[1][r] + p[2][r] + p[3][r];
      su += __shfl_xor(su, 1, 64);
      su += __shfl_xor(su, 2, 64);
      su += __shfl_xor(su, 4, 64);
      su += __shfl_xor(su, 8, 64);
      l_r[r] = l_r[r] * alpha[r] + su;
      m_r[r] = mnew[r];
    }
#pragma unroll
    for (int dt = 0; dt < 4; ++dt)
#pragma unroll
      for (int r = 0; r < 4; ++r) o[dt][r] *= alpha[r];

    // write unnormalized P~ (fp32) + stash P (bf16) for the PV A-operand
#pragma unroll
    for (int nt = 0; nt < 4; ++nt)
#pragma unroll
      for (int r = 0; r < 4; ++r) {
        const int row = w * 16 + q4 * 4 + r;
        const int key = kt * 64 + nt * 16 + l15;
        attn_bh[((size_t)(qbase + row) << 10) + key] = p[nt][r];
        pshm[w][(q4 * 4 + r) * 80 + nt * 16 + l15] = f2bf(p[nt][r]);
      }
    if (l15 == 0) {
#pragma unroll
      for (int r = 0; r < 4; ++r) m_hist[w * 16 + q4 * 4 + r][kt] = mnew[r];
    }

    // O += P V  (A from pshm, B from Vt tile)
    const bf16x8 ap0 = *(const bf16x8*)&pshm[w][l15 * 80 + q4 * 8];
    const bf16x8 ap1 = *(const bf16x8*)&pshm[w][l15 * 80 + 32 + q4 * 8];
#pragma unroll
    for (int dt = 0; dt < 4; ++dt) {
      const bf16x8 bv0 = *(const bf16x8*)&vs[(dt * 16 + l15) * 64 + q4 * 8];
      const bf16x8 bv1 = *(const bf16x8*)&vs[(dt * 16 + l15) * 64 + 32 + q4 * 8];
      o[dt] = __builtin_amdgcn_mfma_f32_16x16x32_bf16(ap0, bv0, o[dt], 0, 0, 0);
      o[dt] = __builtin_amdgcn_mfma_f32_16x16x32_bf16(ap1, bv1, o[dt], 0, 0, 0);
    }
    __syncthreads();
  }

  // finalize ctx (bf16)
  const int bb = bh / 12, h = bh - bb * 12;
  float invl[4];
#pragma unroll
  for (int r = 0; r < 4; ++r) invl[r] = 1.f / l_r[r];
#pragma unroll
  for (int dt = 0; dt < 4; ++dt)
#pragma unroll
    for (int r = 0; r < 4; ++r) {
      const int qrow = qbase + w * 16 + q4 * 4 + r;
      ctx[(size_t)(bb * 1024 + qrow) * 768 + h * 64 + dt * 16 + l15] =
          f2bf(o[dt][r] * invl[r]);
    }

  if (l15 == 0) {
#pragma unroll
    for (int r = 0; r < 4; ++r) {
      mf[w * 16 + q4 * 4 + r] = m_r[r];
      lf[w * 16 + q4 * 4 + r] = l_r[r];
    }
  }

  __threadfence_block();  // order P~ stores before the in-place correction loads

  // correction sweep: attn_final = P~ * exp(m_kt - m_fin) / l_fin (wave-private rows)
  for (int rr = 0; rr < 16; ++rr) {
    const int row = w * 16 + rr;
    const float mfin = mf[row];
    const float li = 1.f / lf[row];
    float* rp = attn_bh + ((size_t)(qbase + row) << 10);
#pragma unroll
    for (int i = 0; i < 4; ++i) {
      const int col = i * 256 + l * 4;
      float4 v = *(float4*)(rp + col);
      const float cc = __expf(m_hist[row][col >> 6] - mfin) * li;
      v.x *= cc; v.y *= cc; v.z *= cc; v.w *= cc;
      *(float4*)(rp + col) = v;
    }
  }
}

// ---------- proj: ctx [8192x768] x wprojT -> out (+bias, fp32) ----------
__global__ __launch_bounds__(256) void k_gemm_proj(
    const unsigned short* __restrict__ A,   // ctx bf16 [8192][768]
    const unsigned short* __restrict__ Bt,  // wprojT bf16 [768][768]
    const float* __restrict__ bias,
    float* __restrict__ out) {
  __shared__ unsigned short As[128 * 32];
  __shared__ unsigned short Bs[128 * 32];
  const int t = threadIdx.x;
  const int w = t >> 6, l = t & 63;
  const int l15 = l & 15, q4 = l >> 4;
  const int wm = w >> 1, wn = w & 1;
  const int m0 = blockIdx.y * 128, n0 = blockIdx.x * 128;

  f32x4 acc[4][4];
#pragma unroll
  for (int i = 0; i < 4; ++i)
#pragma unroll
    for (int j = 0; j < 4; ++j) acc[i][j] = f32x4{0.f, 0.f, 0.f, 0.f};

  const int f2 = t + 256;
  const int ra = t >> 2, ca = (t & 3) * 8;
  const int ra2 = f2 >> 2, ca2 = (f2 & 3) * 8;

  for (int kt = 0; kt < 24; ++kt) {
    const int k0 = kt * 32;
    async_cp16(A + (size_t)(m0 + ra) * 768 + k0 + ca, &As[w * 512]);
    async_cp16(A + (size_t)(m0 + ra2) * 768 + k0 + ca2, &As[2048 + w * 512]);
    async_cp16(Bt + (size_t)(n0 + ra) * 768 + k0 + ca, &Bs[w * 512]);
    async_cp16(Bt + (size_t)(n0 + ra2) * 768 + k0 + ca2, &Bs[2048 + w * 512]);
    __syncthreads();
    bf16x8 a[4], b[4];
#pragma unroll
    for (int mt = 0; mt < 4; ++mt)
      a[mt] = *(const bf16x8*)&As[(wm * 64 + mt * 16 + l15) * 32 + q4 * 8];
#pragma unroll
    for (int nt = 0; nt < 4; ++nt)
      b[nt] = *(const bf16x8*)&Bs[(wn * 64 + nt * 16 + l15) * 32 + q4 * 8];
#pragma unroll
    for (int mt = 0; mt < 4; ++mt)
#pragma unroll
      for (int nt = 0; nt < 4; ++nt)
        acc[mt][nt] = __builtin_amdgcn_mfma_f32_16x16x32_bf16(a[mt], b[nt], acc[mt][nt], 0, 0, 0);
    __syncthreads();
  }

#pragma unroll
  for (int mt = 0; mt < 4; ++mt)
#pragma unroll
    for (int nt = 0; nt < 4; ++nt)
#pragma unroll
      for (int r = 0; r < 4; ++r) {
        const int m = m0 + wm * 64 + mt * 16 + q4 * 4 + r;
        const int n = n0 + wn * 64 + nt * 16 + l15;
        out[(size_t)m * 768 + n] = acc[mt][nt][r] + bias[n];
      }
}

extern "C" void kernel_launch(void* const* d_in, const int* in_sizes, int n_in,
                              void* d_out, int out_size, void* d_ws, size_t ws_size,
                              hipStream_t stream) {
  (void)in_sizes; (void)n_in; (void)out_size; (void)ws_size;
  const float* x      = (const float*)d_in[0];
  const float* w_qkv  = (const float*)d_in[1];
  const float* w_proj = (const float*)d_in[2];
  const float* b_proj = (const float*)d_in[3];
  float* out  = (float*)d_out;
  float* attn = out + (size_t)8 * 1024 * 768;

  char* ws = (char*)d_ws;
  unsigned short* xb     = (unsigned short*)(ws);
  unsigned short* wqkvT  = (unsigned short*)(ws + 12582912);
  unsigned short* wprojT = (unsigned short*)(ws + 16121856);
  unsigned short* Qb     = (unsigned short*)(ws + 17301504);
  unsigned short* Kb     = (unsigned short*)(ws + 17301504 + 12582912);
  unsigned short* Vtb    = (unsigned short*)(ws + 17301504 + 2 * 12582912);
  unsigned short* ctx    = (unsigned short*)(ws + 17301504 + 3 * 12582912);

  k_cvt<<<6144, 256, 0, stream>>>(x, xb, 1572864);
  k_transpose<<<dim3(72, 24), dim3(32, 32), 0, stream>>>(w_qkv, wqkvT, 768, 2304);
  k_transpose<<<dim3(24, 24), dim3(32, 32), 0, stream>>>(w_proj, wprojT, 768, 768);
  k_gemm_qkv<<<dim3(18, 64), 256, 0, stream>>>(xb, wqkvT, Qb, Kb, Vtb);
  k_attn<<<dim3(16, 96), 256, 0, stream>>>(Qb, Kb, Vtb, attn, ctx);
  k_gemm_proj<<<dim3(6, 64), 256, 0, stream>>>(ctx, wprojT, b_proj, out);
}

// Round 2
// 630.798 us; speedup vs baseline: 1.1546x; 1.1546x over previous
//
#include <hip/hip_runtime.h>
#include <stdint.h>

using bf16x8 = __attribute__((ext_vector_type(8))) short;
using f32x4  = __attribute__((ext_vector_type(4))) float;

#define DEVI static __device__ __forceinline__

DEVI unsigned short f2bf(float f) {
  union { float f; unsigned int u; } v; v.f = f;
  return (unsigned short)((v.u + 0x7FFFu + ((v.u >> 16) & 1u)) >> 16);
}

DEVI void async_cp16(const void* g, void* l) {
  __builtin_amdgcn_global_load_lds((__attribute__((address_space(1))) void*)g,
                                   (__attribute__((address_space(3))) void*)l,
                                   16, 0, 0);
}

// ---------- f32 -> bf16 elementwise (x) ----------
__global__ __launch_bounds__(256) void k_cvt(const float* __restrict__ X,
                                             unsigned short* __restrict__ Xb, int n4) {
  int i = blockIdx.x * 256 + threadIdx.x;
  if (i >= n4) return;
  float4 v = ((const float4*)X)[i];
  ushort4 o;
  o.x = f2bf(v.x); o.y = f2bf(v.y); o.z = f2bf(v.z); o.w = f2bf(v.w);
  ((ushort4*)Xb)[i] = o;
}

// ---------- W[Kd][N] f32 -> Wt[N][Kd] bf16 ----------
__global__ __launch_bounds__(1024) void k_transpose(const float* __restrict__ W,
                                                    unsigned short* __restrict__ Wt,
                                                    int Kd, int N) {
  __shared__ float tile[32][33];
  int n0 = blockIdx.x * 32, k0 = blockIdx.y * 32;
  int tx = threadIdx.x, ty = threadIdx.y;
  tile[ty][tx] = W[(size_t)(k0 + ty) * N + n0 + tx];
  __syncthreads();
  Wt[(size_t)(n0 + ty) * Kd + k0 + tx] = f2bf(tile[tx][ty]);
}

// ---------- GEMM1: [8192x768] x [768x2304] -> scatter Q,K,Vt (bf16) ----------
__global__ __launch_bounds__(256) void k_gemm_qkv(
    const unsigned short* __restrict__ A,   // x bf16 [8192][768]
    const unsigned short* __restrict__ Bt,  // wqkvT bf16 [2304][768]
    unsigned short* __restrict__ Q,
    unsigned short* __restrict__ K,
    unsigned short* __restrict__ Vt) {
  __shared__ unsigned short As[128 * 32];
  __shared__ unsigned short Bs[128 * 32];
  const int t = threadIdx.x;
  const int w = t >> 6, l = t & 63;
  const int l15 = l & 15, q4 = l >> 4;
  const int wm = w >> 1, wn = w & 1;
  const int m0 = blockIdx.y * 128, n0 = blockIdx.x * 128;

  f32x4 acc[4][4];
#pragma unroll
  for (int i = 0; i < 4; ++i)
#pragma unroll
    for (int j = 0; j < 4; ++j) acc[i][j] = f32x4{0.f, 0.f, 0.f, 0.f};

  const int f2 = t + 256;
  const int ra = t >> 2, ca = (t & 3) * 8;
  const int ra2 = f2 >> 2, ca2 = (f2 & 3) * 8;

  for (int kt = 0; kt < 24; ++kt) {
    const int k0 = kt * 32;
    async_cp16(A + (size_t)(m0 + ra) * 768 + k0 + ca, &As[w * 512]);
    async_cp16(A + (size_t)(m0 + ra2) * 768 + k0 + ca2, &As[2048 + w * 512]);
    async_cp16(Bt + (size_t)(n0 + ra) * 768 + k0 + ca, &Bs[w * 512]);
    async_cp16(Bt + (size_t)(n0 + ra2) * 768 + k0 + ca2, &Bs[2048 + w * 512]);
    __syncthreads();
    bf16x8 a[4], b[4];
#pragma unroll
    for (int mt = 0; mt < 4; ++mt)
      a[mt] = *(const bf16x8*)&As[(wm * 64 + mt * 16 + l15) * 32 + q4 * 8];
#pragma unroll
    for (int nt = 0; nt < 4; ++nt)
      b[nt] = *(const bf16x8*)&Bs[(wn * 64 + nt * 16 + l15) * 32 + q4 * 8];
#pragma unroll
    for (int mt = 0; mt < 4; ++mt)
#pragma unroll
      for (int nt = 0; nt < 4; ++nt)
        acc[mt][nt] = __builtin_amdgcn_mfma_f32_16x16x32_bf16(a[mt], b[nt], acc[mt][nt], 0, 0, 0);
    __syncthreads();
  }

  const int which = n0 / 768;  // 0=q 1=k 2=v (128 | 768, so uniform per block)
#pragma unroll
  for (int mt = 0; mt < 4; ++mt)
#pragma unroll
    for (int nt = 0; nt < 4; ++nt)
#pragma unroll
      for (int r = 0; r < 4; ++r) {
        const int m = m0 + wm * 64 + mt * 16 + q4 * 4 + r;
        const int n = n0 + wn * 64 + nt * 16 + l15;
        const int c = n - which * 768;
        const int h = c >> 6, d = c & 63;
        const int bb = m >> 10, nn = m & 1023;
        const int bh = bb * 12 + h;
        const unsigned short val = f2bf(acc[mt][nt][r]);
        if (which == 0)
          Q[(size_t)(bh * 1024 + nn) * 64 + d] = val;
        else if (which == 1)
          K[(size_t)(bh * 1024 + nn) * 64 + d] = val;
        else
          Vt[(size_t)(bh * 64 + d) * 1024 + nn] = val;  // transposed for PV B-frags
      }
}

// ---------- attention: two-pass (S^T layout), writes FINAL attn once ----------
__global__ __launch_bounds__(256) void k_attn(
    const unsigned short* __restrict__ Q,
    const unsigned short* __restrict__ Kg,
    const unsigned short* __restrict__ Vt,
    float* __restrict__ attn,
    unsigned short* __restrict__ ctx) {
  __shared__ __align__(16) unsigned short qs[64 * 64];
  __shared__ __align__(16) unsigned short ks[64 * 64];
  __shared__ __align__(16) unsigned short vs[64 * 64];       // [d][key_local]
  __shared__ __align__(16) unsigned short pshm[4][16 * 72];  // [q_local][key], stride 72

  const int t = threadIdx.x;
  const int w = t >> 6, l = t & 63;
  const int l15 = l & 15, q4 = l >> 4;
  const int qb = blockIdx.x, bh = blockIdx.y;
  const int qbase = qb * 64;

  {  // stage Q tile once (contiguous 8 KiB, lives through both passes)
    const size_t qoff = ((size_t)bh * 1024 + qbase) * 64;
    async_cp16(Q + qoff + (size_t)t * 8, &qs[w * 512]);
    async_cp16(Q + qoff + (size_t)(t + 256) * 8, &qs[2048 + w * 512]);
  }

  float m_run = -__builtin_inff(), l_run = 0.f;

  const int vrow = t >> 3, vcol = (t & 7) * 8;
  const int vrow2 = (t + 256) >> 3, vcol2 = ((t + 256) & 7) * 8;
  float* const attn_bh = attn + ((size_t)bh << 20);

  // ---- pass 1: exact row max m and denominator l (nothing written) ----
  for (int kt = 0; kt < 16; ++kt) {
    {
      const size_t koff = ((size_t)bh * 1024 + kt * 64) * 64;
      async_cp16(Kg + koff + (size_t)t * 8, &ks[w * 512]);
      async_cp16(Kg + koff + (size_t)(t + 256) * 8, &ks[2048 + w * 512]);
    }
    __syncthreads();

    // S^T = K Q^T * scale : wave w owns q-cols (w*16 + l15), keys in rows
    const bf16x8 bq0 = *(const bf16x8*)&qs[(w * 16 + l15) * 64 + q4 * 8];
    const bf16x8 bq1 = *(const bf16x8*)&qs[(w * 16 + l15) * 64 + 32 + q4 * 8];
    f32x4 sv[4];
#pragma unroll
    for (int nt = 0; nt < 4; ++nt) {
      const bf16x8 ak0 = *(const bf16x8*)&ks[(nt * 16 + l15) * 64 + q4 * 8];
      const bf16x8 ak1 = *(const bf16x8*)&ks[(nt * 16 + l15) * 64 + 32 + q4 * 8];
      f32x4 z = f32x4{0.f, 0.f, 0.f, 0.f};
      z = __builtin_amdgcn_mfma_f32_16x16x32_bf16(ak0, bq0, z, 0, 0, 0);
      z = __builtin_amdgcn_mfma_f32_16x16x32_bf16(ak1, bq1, z, 0, 0, 0);
      sv[nt] = z * 0.125f;
    }

    float tmax = -__builtin_inff();
#pragma unroll
    for (int nt = 0; nt < 4; ++nt)
#pragma unroll
      for (int r = 0; r < 4; ++r) tmax = fmaxf(tmax, sv[nt][r]);
    tmax = fmaxf(tmax, __shfl_xor(tmax, 16, 64));
    tmax = fmaxf(tmax, __shfl_xor(tmax, 32, 64));
    const float mnew = fmaxf(m_run, tmax);
    float sum = 0.f;
#pragma unroll
    for (int nt = 0; nt < 4; ++nt)
#pragma unroll
      for (int r = 0; r < 4; ++r) sum += __expf(sv[nt][r] - mnew);
    sum += __shfl_xor(sum, 16, 64);
    sum += __shfl_xor(sum, 32, 64);
    l_run = l_run * __expf(m_run - mnew) + sum;
    m_run = mnew;
    __syncthreads();
  }

  const float m_fin = m_run;
  const float invl = 1.f / l_run;

  f32x4 o[4];
#pragma unroll
  for (int dt = 0; dt < 4; ++dt) o[dt] = f32x4{0.f, 0.f, 0.f, 0.f};

  // ---- pass 2: recompute S, write final attn directly, accumulate PV ----
  for (int kt = 0; kt < 16; ++kt) {
    {
      const size_t koff = ((size_t)bh * 1024 + kt * 64) * 64;
      async_cp16(Kg + koff + (size_t)t * 8, &ks[w * 512]);
      async_cp16(Kg + koff + (size_t)(t + 256) * 8, &ks[2048 + w * 512]);
      const size_t vbase = (size_t)bh * 65536 + kt * 64;
      async_cp16(Vt + vbase + (size_t)vrow * 1024 + vcol, &vs[w * 512]);
      async_cp16(Vt + vbase + (size_t)vrow2 * 1024 + vcol2, &vs[2048 + w * 512]);
    }
    __syncthreads();

    const bf16x8 bq0 = *(const bf16x8*)&qs[(w * 16 + l15) * 64 + q4 * 8];
    const bf16x8 bq1 = *(const bf16x8*)&qs[(w * 16 + l15) * 64 + 32 + q4 * 8];
    float* const arow = attn_bh + (((size_t)(qbase + w * 16 + l15)) << 10) + kt * 64;
#pragma unroll
    for (int nt = 0; nt < 4; ++nt) {
      const bf16x8 ak0 = *(const bf16x8*)&ks[(nt * 16 + l15) * 64 + q4 * 8];
      const bf16x8 ak1 = *(const bf16x8*)&ks[(nt * 16 + l15) * 64 + 32 + q4 * 8];
      f32x4 z = f32x4{0.f, 0.f, 0.f, 0.f};
      z = __builtin_amdgcn_mfma_f32_16x16x32_bf16(ak0, bq0, z, 0, 0, 0);
      z = __builtin_amdgcn_mfma_f32_16x16x32_bf16(ak1, bq1, z, 0, 0, 0);
      // p = exp(s - m_fin); final attn = p * invl; stash p (bf16) for PV
      f32x4 p;
#pragma unroll
      for (int r = 0; r < 4; ++r) p[r] = __expf(z[r] * 0.125f - m_fin);
      __builtin_nontemporal_store(p * invl, (f32x4*)(arow + nt * 16 + q4 * 4));
      ushort4 pk;
      pk.x = f2bf(p[0]); pk.y = f2bf(p[1]); pk.z = f2bf(p[2]); pk.w = f2bf(p[3]);
      *(ushort4*)&pshm[w][l15 * 72 + nt * 16 + q4 * 4] = pk;
    }

    // O += P V  (A = P from pshm [q][key], B = V^T tile [d][key])
    const bf16x8 ap0 = *(const bf16x8*)&pshm[w][l15 * 72 + q4 * 8];
    const bf16x8 ap1 = *(const bf16x8*)&pshm[w][l15 * 72 + 32 + q4 * 8];
#pragma unroll
    for (int dt = 0; dt < 4; ++dt) {
      const bf16x8 bv0 = *(const bf16x8*)&vs[(dt * 16 + l15) * 64 + q4 * 8];
      const bf16x8 bv1 = *(const bf16x8*)&vs[(dt * 16 + l15) * 64 + 32 + q4 * 8];
      o[dt] = __builtin_amdgcn_mfma_f32_16x16x32_bf16(ap0, bv0, o[dt], 0, 0, 0);
      o[dt] = __builtin_amdgcn_mfma_f32_16x16x32_bf16(ap1, bv1, o[dt], 0, 0, 0);
    }
    __syncthreads();
  }

  // finalize ctx (bf16): o rows are q_local = q4*4+r, col = d = dt*16+l15
  const int bb = bh / 12, h = bh - bb * 12;
  float invl_r[4];
#pragma unroll
  for (int r = 0; r < 4; ++r) invl_r[r] = __shfl(invl, q4 * 4 + r, 64);
#pragma unroll
  for (int dt = 0; dt < 4; ++dt)
#pragma unroll
    for (int r = 0; r < 4; ++r) {
      const int qrow = qbase + w * 16 + q4 * 4 + r;
      ctx[(size_t)(bb * 1024 + qrow) * 768 + h * 64 + dt * 16 + l15] =
          f2bf(o[dt][r] * invl_r[r]);
    }
}

// ---------- proj: ctx [8192x768] x wprojT -> out (+bias, fp32) ----------
__global__ __launch_bounds__(256) void k_gemm_proj(
    const unsigned short* __restrict__ A,   // ctx bf16 [8192][768]
    const unsigned short* __restrict__ Bt,  // wprojT bf16 [768][768]
    const float* __restrict__ bias,
    float* __restrict__ out) {
  __shared__ unsigned short As[128 * 32];
  __shared__ unsigned short Bs[128 * 32];
  const int t = threadIdx.x;
  const int w = t >> 6, l = t & 63;
  const int l15 = l & 15, q4 = l >> 4;
  const int wm = w >> 1, wn = w & 1;
  const int m0 = blockIdx.y * 128, n0 = blockIdx.x * 128;

  f32x4 acc[4][4];
#pragma unroll
  for (int i = 0; i < 4; ++i)
#pragma unroll
    for (int j = 0; j < 4; ++j) acc[i][j] = f32x4{0.f, 0.f, 0.f, 0.f};

  const int f2 = t + 256;
  const int ra = t >> 2, ca = (t & 3) * 8;
  const int ra2 = f2 >> 2, ca2 = (f2 & 3) * 8;

  for (int kt = 0; kt < 24; ++kt) {
    const int k0 = kt * 32;
    async_cp16(A + (size_t)(m0 + ra) * 768 + k0 + ca, &As[w * 512]);
    async_cp16(A + (size_t)(m0 + ra2) * 768 + k0 + ca2, &As[2048 + w * 512]);
    async_cp16(Bt + (size_t)(n0 + ra) * 768 + k0 + ca, &Bs[w * 512]);
    async_cp16(Bt + (size_t)(n0 + ra2) * 768 + k0 + ca2, &Bs[2048 + w * 512]);
    __syncthreads();
    bf16x8 a[4], b[4];
#pragma unroll
    for (int mt = 0; mt < 4; ++mt)
      a[mt] = *(const bf16x8*)&As[(wm * 64 + mt * 16 + l15) * 32 + q4 * 8];
#pragma unroll
    for (int nt = 0; nt < 4; ++nt)
      b[nt] = *(const bf16x8*)&Bs[(wn * 64 + nt * 16 + l15) * 32 + q4 * 8];
#pragma unroll
    for (int mt = 0; mt < 4; ++mt)
#pragma unroll
      for (int nt = 0; nt < 4; ++nt)
        acc[mt][nt] = __builtin_amdgcn_mfma_f32_16x16x32_bf16(a[mt], b[nt], acc[mt][nt], 0, 0, 0);
    __syncthreads();
  }

#pragma unroll
  for (int mt = 0; mt < 4; ++mt)
#pragma unroll
    for (int nt = 0; nt < 4; ++nt)
#pragma unroll
      for (int r = 0; r < 4; ++r) {
        const int m = m0 + wm * 64 + mt * 16 + q4 * 4 + r;
        const int n = n0 + wn * 64 + nt * 16 + l15;
        out[(size_t)m * 768 + n] = acc[mt][nt][r] + bias[n];
      }
}

extern "C" void kernel_launch(void* const* d_in, const int* in_sizes, int n_in,
                              void* d_out, int out_size, void* d_ws, size_t ws_size,
                              hipStream_t stream) {
  (void)in_sizes; (void)n_in; (void)out_size; (void)ws_size;
  const float* x      = (const float*)d_in[0];
  const float* w_qkv  = (const float*)d_in[1];
  const float* w_proj = (const float*)d_in[2];
  const float* b_proj = (const float*)d_in[3];
  float* out  = (float*)d_out;
  float* attn = out + (size_t)8 * 1024 * 768;

  char* ws = (char*)d_ws;
  unsigned short* xb     = (unsigned short*)(ws);
  unsigned short* wqkvT  = (unsigned short*)(ws + 12582912);
  unsigned short* wprojT = (unsigned short*)(ws + 16121856);
  unsigned short* Qb     = (unsigned short*)(ws + 17301504);
  unsigned short* Kb     = (unsigned short*)(ws + 17301504 + 12582912);
  unsigned short* Vtb    = (unsigned short*)(ws + 17301504 + 2 * 12582912);
  unsigned short* ctx    = (unsigned short*)(ws + 17301504 + 3 * 12582912);

  k_cvt<<<6144, 256, 0, stream>>>(x, xb, 1572864);
  k_transpose<<<dim3(72, 24), dim3(32, 32), 0, stream>>>(w_qkv, wqkvT, 768, 2304);
  k_transpose<<<dim3(24, 24), dim3(32, 32), 0, stream>>>(w_proj, wprojT, 768, 768);
  k_gemm_qkv<<<dim3(18, 64), 256, 0, stream>>>(xb, wqkvT, Qb, Kb, Vtb);
  k_attn<<<dim3(16, 96), 256, 0, stream>>>(Qb, Kb, Vtb, attn, ctx);
  k_gemm_proj<<<dim3(6, 64), 256, 0, stream>>>(ctx, wprojT, b_proj, out);
}